// Round 4
// baseline (549.097 us; speedup 1.0000x reference)
//
#include <hip/hip_runtime.h>
#include <hip/hip_bf16.h>

// Performer-style linear attention: B=4, S=8192, H=768, NH=12, HD=64, M=64.
// Round 8: tail restructure via WKV factorization.
//   out[s,c] = sum_{h,m} (qp[b,h,s,m]/(n+eps)) * WKV[b,h,m,c] + bo,
//   WKV[b,h,m,c] = sum_d kv[b,h,m,d] * Wo[h*64+d, c].
// Deletes ctx materialization (100 MB round-trip) and the fused ctx_out kernel.
// ksum now accumulated in gemm_qkv's k-epilogue (fp32 partials + atomics).
// build_cat rewritten as coalesced LDS tile-transpose.
// Pipeline:
//   K0 zero kvM[48][64][64] + ksumF[48][64]
//   K1 cvt hs -> bf16
//   K2 fold P into Wq/Wk (Wqp = Wq * blockdiag(P)) [fp32]
//   K3 build B^T concat weights [Wqp|Wkp|Wv] + WoT as bf16 (tile transpose), bias
//   K4 gemm_qkv (persistent 128x128, r3 structure) -> qp, kpT, vT, ksumF
//   K5 kv_accum_mfma -> kvM[bh][m][d] fp32
//   K6 wkv_build: WKVT[b][c][h*64+m] = sum_d WoT[c][h*64+d]*kv[m][d]  (VALU)
//   K7 qpn_scale: n = qp . ksum; ctx[b][s][h*64+m] = bf16(qp/(n+eps))
//   K8 out_gemm: out = ctx @ WKVT[b]^T + bo   (m97-style 128x128, BK=32)

#define S_    8192
#define H_    768
#define NH_   12
#define EPS_  1e-6f

typedef unsigned short U16;
typedef short bf16x8 __attribute__((ext_vector_type(8)));
typedef float f32x4  __attribute__((ext_vector_type(4)));

__device__ __forceinline__ U16 f2b(float x) {            // fp32 -> bf16 RNE
  unsigned u = __float_as_uint(x);
  return (U16)((u + 0x7fffu + ((u >> 16) & 1u)) >> 16);
}
__device__ __forceinline__ float b2f(U16 h) {
  return __uint_as_float(((unsigned)h) << 16);
}
__device__ __forceinline__ void gl2lds16(const void* g, void* l) {
  __builtin_amdgcn_global_load_lds(
      (const __attribute__((address_space(1))) void*)g,
      (__attribute__((address_space(3))) void*)l, 16, 0, 0);
}

// ---------- K0: zero scratch ----------
__global__ void zero_f32(float* __restrict__ p, int n) {
  int i = blockIdx.x * 256 + threadIdx.x;
  if (i < n) p[i] = 0.f;
}

// ---------- K1: fp32 -> bf16 ----------
__global__ void cvt_f32_bf16(const float* __restrict__ src, U16* __restrict__ hi, int n4) {
  int i = blockIdx.x * 256 + threadIdx.x;
  if (i >= n4) return;
  float4 x = ((const float4*)src)[i];
  ushort4 h;
  h.x = f2b(x.x); h.y = f2b(x.y); h.z = f2b(x.z); h.w = f2b(x.w);
  ((ushort4*)hi)[i] = h;
}

// ---------- K2: fold P into Wq / Wk (and biases) ----------
__global__ void fold_proj(const float* __restrict__ Wq, const float* __restrict__ bq,
                          const float* __restrict__ Wk, const float* __restrict__ bk,
                          const float* __restrict__ P,
                          float* __restrict__ Wqp, float* __restrict__ bqp,
                          float* __restrict__ Wkp, float* __restrict__ bkp) {
  __shared__ float Pl[64 * 64];
  __shared__ float WL[4 * 64];
  int h = blockIdx.y, kc = blockIdx.x, tid = threadIdx.x;
  const float* W  = blockIdx.z ? Wk : Wq;
  const float* bb = blockIdx.z ? bk : bq;
  float* Wout = blockIdx.z ? Wkp : Wqp;
  float* bout = blockIdx.z ? bkp : bqp;
  const float4* P4 = (const float4*)(P + (size_t)h * 4096);
#pragma unroll
  for (int i = 0; i < 4; ++i) ((float4*)Pl)[tid + i * 256] = P4[tid + i * 256];
  WL[tid] = W[(size_t)(kc * 4 + (tid >> 6)) * H_ + h * 64 + (tid & 63)];
  __syncthreads();
  int kl = tid >> 6, m = tid & 63;
  float acc = 0.f;
#pragma unroll
  for (int d = 0; d < 64; ++d) acc += WL[kl * 64 + d] * Pl[d * 64 + m];
  Wout[(size_t)(kc * 4 + kl) * H_ + h * 64 + m] = acc;
  if (kc == 0 && tid < 64) {
    float a2 = 0.f;
    for (int d = 0; d < 64; ++d) a2 += bb[h * 64 + d] * Pl[d * 64 + tid];
    bout[h * 64 + tid] = a2;
  }
}

// ---------- K3: coalesced tile-transpose build of bf16 weights ----------
// grid (12 kb, 12 rb, 4 mat): out[r][k] = W[k][r] as bf16.
__global__ void build_cat_t(const float* __restrict__ Wqp, const float* __restrict__ Wkp,
                            const float* __restrict__ Wv,  const float* __restrict__ Wo,
                            U16* __restrict__ WcatH, U16* __restrict__ WoTH) {
  __shared__ float T[64][68];
  const int kb = blockIdx.x, rb = blockIdx.y, mat = blockIdx.z;
  const int tid = threadIdx.x;
  const float* W = mat == 0 ? Wqp : (mat == 1 ? Wkp : (mat == 2 ? Wv : Wo));
#pragma unroll
  for (int p = 0; p < 4; ++p) {
    int idx = tid + p * 256;                 // 1024 float4s
    int rr = idx >> 4, c4 = (idx & 15) * 4;
    float4 v = *(const float4*)&W[(size_t)(kb * 64 + rr) * H_ + rb * 64 + c4];
    T[rr][c4] = v.x; T[rr][c4 + 1] = v.y; T[rr][c4 + 2] = v.z; T[rr][c4 + 3] = v.w;
  }
  __syncthreads();
  U16* dst = mat == 3 ? WoTH : WcatH;
  const int rbase = (mat == 3 ? 0 : mat * 768) + rb * 64;
#pragma unroll
  for (int p = 0; p < 4; ++p) {
    int idx = tid + p * 256;                 // 4096 ushort4s
    int r2 = idx >> 4, c2 = (idx & 15) * 4;
    ushort4 o;
    o.x = f2b(T[c2 + 0][r2]); o.y = f2b(T[c2 + 1][r2]);
    o.z = f2b(T[c2 + 2][r2]); o.w = f2b(T[c2 + 3][r2]);
    *(ushort4*)&dst[(size_t)(rbase + r2) * H_ + kb * 64 + c2] = o;
  }
}

__global__ void build_bias(const float* __restrict__ bqp, const float* __restrict__ bkp,
                           const float* __restrict__ bv, float* __restrict__ biasC) {
  int i = blockIdx.x * 256 + threadIdx.x;
  if (i >= 2304) return;
  biasC[i] = i < 768 ? bqp[i] : (i < 1536 ? bkp[i - 768] : bv[i - 1536]);
}

// ---------- K4: persistent 128x128 bf16 GEMM + fused maxexp epilogue ----------
// (r3 structure) + ksum accumulation for k-columns (fp32 partials + atomics).
__global__ __launch_bounds__(256, 2) void gemm_qkv(
    const U16* __restrict__ Ahi, const U16* __restrict__ Bhi,
    const float* __restrict__ bias,
    U16* __restrict__ qp, U16* __restrict__ kpT, U16* __restrict__ vT,
    float* __restrict__ ksumF) {
  __shared__ __align__(16) U16 Us[32768];            // [buf][A/B][128][64] bf16
  const int tid = threadIdx.x, w = tid >> 6, lane = tid & 63;
  const int quad = lane >> 4, l16 = lane & 15;
  const int b = blockIdx.x;                          // 512 persistent blocks
  const int mt = b & 255, nt0 = b >> 8;
  const int rowA0 = mt * 128;
  const int wm = w & 1, wn = w >> 1;
  const U16* srcA[4];
  int rowBl[4];
  unsigned ldsc[4];
  const int kch = ((lane & 7) ^ (lane >> 3)) * 8;    // pre-swizzled src chunk
#pragma unroll
  for (int t = 0; t < 4; ++t) {
    int c = w * 4 + t;
    int row = c * 8 + (lane >> 3);
    srcA[t] = Ahi + (size_t)(rowA0 + row) * H_ + kch;
    rowBl[t] = row;
    ldsc[t] = (unsigned)c * 512;
  }
  auto stage = [&](int jn, int tn, int bi) {
    const int colB = (nt0 + 2 * jn) * 128;
    unsigned ub = (unsigned)bi * 16384u;
#pragma unroll
    for (int t = 0; t < 4; ++t) {
      gl2lds16(srcA[t] + tn * 64, &Us[ub + ldsc[t]]);
      gl2lds16(Bhi + (size_t)(colB + rowBl[t]) * H_ + tn * 64 + kch,
               &Us[ub + 8192u + ldsc[t]]);
    }
  };

  stage(0, 0, 0);
  for (int jj = 0; jj < 9; ++jj) {
    const int colB0 = (nt0 + 2 * jj) * 128;
    f32x4 acc[4][4] = {};
    for (int t = 0; t < 12; ++t) {
      const bool more = !(jj == 8 && t == 11);
      if (more) {
        if (t < 11) stage(jj, t + 1, (t + 1) & 1);
        else        stage(jj + 1, 0, 0);
        asm volatile("s_waitcnt vmcnt(8)" ::: "memory");
      } else {
        asm volatile("s_waitcnt vmcnt(0)" ::: "memory");
      }
      __builtin_amdgcn_sched_barrier(0);
      __builtin_amdgcn_s_barrier();
      __builtin_amdgcn_sched_barrier(0);
      const unsigned ab = (unsigned)(t & 1) * 16384u;
      bf16x8 ah[4][2], bh[4][2];
#pragma unroll
      for (int i = 0; i < 4; ++i)
#pragma unroll
        for (int ks = 0; ks < 2; ++ks)
          ah[i][ks] = *(const bf16x8*)&Us[ab +
              (unsigned)((wm * 64 + i * 16 + l16) * 64 +
                         (((ks * 4 + quad) ^ (l16 & 7)) * 8))];
#pragma unroll
      for (int j = 0; j < 4; ++j)
#pragma unroll
        for (int ks = 0; ks < 2; ++ks)
          bh[j][ks] = *(const bf16x8*)&Us[ab + 8192u +
              (unsigned)((wn * 64 + j * 16 + l16) * 64 +
                         (((ks * 4 + quad) ^ (l16 & 7)) * 8))];
      asm volatile("s_waitcnt lgkmcnt(0)" ::: "memory");
      __builtin_amdgcn_sched_barrier(0);
      __builtin_amdgcn_s_setprio(1);
#pragma unroll
      for (int ks = 0; ks < 2; ++ks)
#pragma unroll
        for (int j = 0; j < 4; ++j)
#pragma unroll
          for (int i = 0; i < 4; ++i)
            acc[i][j] = __builtin_amdgcn_mfma_f32_16x16x32_bf16(
                ah[i][ks], bh[j][ks], acc[i][j], 0, 0, 0);
      __builtin_amdgcn_s_setprio(0);
      __builtin_amdgcn_sched_barrier(0);
      __builtin_amdgcn_s_barrier();
      __builtin_amdgcn_sched_barrier(0);
    }
    // ---- epilogue for this tile (no LDS use; overlaps next stage)
    const int col64 = colB0 + wn * 64;
    float bj[4];
#pragma unroll
    for (int j = 0; j < 4; ++j) bj[j] = bias[col64 + j * 16 + l16];
    if (col64 < 768) {                            // q logits -> row-major qp
      const int h = col64 >> 6;
#pragma unroll
      for (int i = 0; i < 4; ++i) {
#pragma unroll
        for (int r = 0; r < 4; ++r) {
          int row = rowA0 + wm * 64 + i * 16 + quad * 4 + r;
          float v0 = acc[i][0][r] + bj[0], v1 = acc[i][1][r] + bj[1];
          float v2 = acc[i][2][r] + bj[2], v3 = acc[i][3][r] + bj[3];
          float mx = fmaxf(fmaxf(v0, v1), fmaxf(v2, v3));
          mx = fmaxf(mx, __shfl_xor(mx, 1));
          mx = fmaxf(mx, __shfl_xor(mx, 2));
          mx = fmaxf(mx, __shfl_xor(mx, 4));
          mx = fmaxf(mx, __shfl_xor(mx, 8));
          int bb = row >> 13, s = row & 8191;
          size_t base = ((size_t)(bb * NH_ + h) * S_ + s) * 64 + l16;
          qp[base +  0] = f2b(__expf(v0 - mx));
          qp[base + 16] = f2b(__expf(v1 - mx));
          qp[base + 32] = f2b(__expf(v2 - mx));
          qp[base + 48] = f2b(__expf(v3 - mx));
        }
      }
    } else {                                      // k (exp) or v -> transposed
      const int isv = col64 >= 1536;
      const int h = (col64 - (isv ? 1536 : 768)) >> 6;
      U16* dstT = isv ? vT : kpT;
      const int bh2 = (rowA0 >> 13) * NH_ + h;
      float pk[4] = {0.f, 0.f, 0.f, 0.f};
#pragma unroll
      for (int i = 0; i < 4; ++i) {
        float er[4][4];                           // [j][r]
#pragma unroll
        for (int r = 0; r < 4; ++r) {
          float v0 = acc[i][0][r] + bj[0], v1 = acc[i][1][r] + bj[1];
          float v2 = acc[i][2][r] + bj[2], v3 = acc[i][3][r] + bj[3];
          if (!isv) {
            float mx = fmaxf(fmaxf(v0, v1), fmaxf(v2, v3));
            mx = fmaxf(mx, __shfl_xor(mx, 1));
            mx = fmaxf(mx, __shfl_xor(mx, 2));
            mx = fmaxf(mx, __shfl_xor(mx, 4));
            mx = fmaxf(mx, __shfl_xor(mx, 8));
            v0 = __expf(v0 - mx); v1 = __expf(v1 - mx);
            v2 = __expf(v2 - mx); v3 = __expf(v3 - mx);
          }
          er[0][r] = v0; er[1][r] = v1; er[2][r] = v2; er[3][r] = v3;
        }
        if (!isv) {
#pragma unroll
          for (int j = 0; j < 4; ++j)
            pk[j] += er[j][0] + er[j][1] + er[j][2] + er[j][3];
        }
        int n = rowA0 + wm * 64 + i * 16 + quad * 4;   // 4-aligned
        int s = n & 8191;
#pragma unroll
        for (int j = 0; j < 4; ++j) {
          ushort4 o;
          o.x = f2b(er[j][0]); o.y = f2b(er[j][1]);
          o.z = f2b(er[j][2]); o.w = f2b(er[j][3]);
          *(ushort4*)&dstT[((size_t)bh2 * 64 + j * 16 + l16) * S_ + s] = o;
        }
      }
      if (!isv) {                                  // ksum partial (64 rows)
#pragma unroll
        for (int j = 0; j < 4; ++j) {
          pk[j] += __shfl_xor(pk[j], 16);
          pk[j] += __shfl_xor(pk[j], 32);
        }
        if (quad == 0) {
#pragma unroll
          for (int j = 0; j < 4; ++j)
            atomicAdd(&ksumF[bh2 * 64 + j * 16 + l16], pk[j]);
        }
      }
    }
  }
}

// ---------- K5: kv summary via MFMA -> kvM[bh][m][d] fp32 ----------
__global__ __launch_bounds__(256, 4) void kv_accum_mfma(
    const U16* __restrict__ kpT, const U16* __restrict__ vT,
    float* __restrict__ kvM) {
  __shared__ __align__(16) U16 Us[2 * 64 * 64];   // [0:4096]=vT tile, [4096:8192]=kpT
  const int tid = threadIdx.x, w = tid >> 6, lane = tid & 63;
  const int quad = lane >> 4, l16 = lane & 15;
  const int bh = blockIdx.y;
  const int n0 = blockIdx.x * 512;
  const U16* srcs[4];
  unsigned ldsoff[4];
#pragma unroll
  for (int t = 0; t < 4; ++t) {
    int c = w * 4 + t, buf = c >> 3;              // 0..15; buf 0 = vT, 1 = kpT
    int r = (c & 7) * 8 + (lane >> 3);
    const U16* base = buf ? kpT : vT;
    srcs[t] = base + ((size_t)bh * 64 + r) * S_ + n0 + (lane & 7) * 8;
    ldsoff[t] = buf * 4096 + (c & 7) * 512;
  }
  f32x4 acc[4] = {};
  for (int nc = 0; nc < 512; nc += 64) {
#pragma unroll
    for (int t = 0; t < 4; ++t) gl2lds16(srcs[t] + nc, &Us[ldsoff[t]]);
    __syncthreads();
#pragma unroll
    for (int k0 = 0; k0 < 64; k0 += 32) {
      bf16x8 av = *(const bf16x8*)&Us[(w * 16 + l16) * 64 + k0 + quad * 8];
#pragma unroll
      for (int j = 0; j < 4; ++j) {
        bf16x8 bk = *(const bf16x8*)&Us[4096 + (j * 16 + l16) * 64 + k0 + quad * 8];
        acc[j] = __builtin_amdgcn_mfma_f32_16x16x32_bf16(av, bk, acc[j], 0, 0, 0);
      }
    }
    __syncthreads();
  }
  // acc[j][r]: d = w*16+quad*4+r, m = j*16+l16 -> kvM[bh][m][d]
#pragma unroll
  for (int j = 0; j < 4; ++j)
#pragma unroll
    for (int r = 0; r < 4; ++r)
      atomicAdd(&kvM[((size_t)bh * 64 + j * 16 + l16) * 64 + w * 16 + quad * 4 + r],
                acc[j][r]);
}

// ---------- K6: WKVT[b][c][h*64+m] = sum_d WoT[c][h*64+d] * kv[m][d] ----------
// grid (6 cB, 48 bh), 256 threads, VALU (302 MFLOP total).
__global__ __launch_bounds__(256) void wkv_build(
    const float* __restrict__ kvM, const U16* __restrict__ WoTH,
    U16* __restrict__ WKVT) {
  __shared__ float kvL[64][65];
  __shared__ U16  WoL[128][66];
  const int tid = threadIdx.x;
  const int cB = blockIdx.x * 128, bh = blockIdx.y;
  const int b = bh / NH_, h = bh - b * NH_;
#pragma unroll
  for (int p = 0; p < 16; ++p) {
    int idx = tid + p * 256;                   // 4096 floats
    kvL[idx >> 6][idx & 63] = kvM[(size_t)bh * 4096 + idx];
  }
#pragma unroll
  for (int p = 0; p < 32; ++p) {
    int idx = tid + p * 256;                   // 8192 u16
    WoL[idx >> 6][idx & 63] = WoTH[(size_t)(cB + (idx >> 6)) * H_ + h * 64 + (idx & 63)];
  }
  __syncthreads();
  const int c = tid & 127, m0 = (tid >> 7) * 32;
  float acc[32] = {};
  for (int d = 0; d < 64; ++d) {
    float wv = b2f(WoL[c][d]);
#pragma unroll
    for (int mm = 0; mm < 32; ++mm) acc[mm] += wv * kvL[m0 + mm][d];
  }
  U16* dst = WKVT + (size_t)b * 589824 + (size_t)(cB + c) * H_ + h * 64 + m0;
#pragma unroll
  for (int mm = 0; mm < 32; mm += 4) {
    ushort4 o;
    o.x = f2b(acc[mm]); o.y = f2b(acc[mm + 1]);
    o.z = f2b(acc[mm + 2]); o.w = f2b(acc[mm + 3]);
    *(ushort4*)&dst[mm] = o;
  }
}

// ---------- K7: qpn = qp/(n+eps), transposed to [b][s][h*64+m] ----------
// grid (128 s-chunks, 48 bh), 256 threads: 64 rows/block, 4 threads/row.
__global__ __launch_bounds__(256) void qpn_scale(
    const U16* __restrict__ qp, const float* __restrict__ ksumF,
    U16* __restrict__ ctx) {
  __shared__ float ks[64];
  const int tid = threadIdx.x;
  const int bh = blockIdx.y, s0 = blockIdx.x * 64;
  if (tid < 64) ks[tid] = ksumF[bh * 64 + tid];
  __syncthreads();
  const int row = tid >> 2, q = tid & 3;
  size_t src = ((size_t)bh * S_ + s0 + row) * 64 + q * 16;
  bf16x8 x0 = *(const bf16x8*)&qp[src];
  bf16x8 x1 = *(const bf16x8*)&qp[src + 8];
  float f[16];
  float n = 0.f;
#pragma unroll
  for (int e = 0; e < 8; ++e) {
    f[e] = b2f((U16)x0[e]);     n += f[e] * ks[q * 16 + e];
    f[e + 8] = b2f((U16)x1[e]); n += f[e + 8] * ks[q * 16 + 8 + e];
  }
  n += __shfl_xor(n, 1);
  n += __shfl_xor(n, 2);
  const float inv = 1.f / (n + EPS_);
  const int b = bh / NH_, h = bh - b * NH_;
  U16* dst = ctx + ((size_t)(b * S_ + s0 + row)) * H_ + h * 64 + q * 16;
#pragma unroll
  for (int g = 0; g < 4; ++g) {
    ushort4 o;
    o.x = f2b(f[g * 4 + 0] * inv); o.y = f2b(f[g * 4 + 1] * inv);
    o.z = f2b(f[g * 4 + 2] * inv); o.w = f2b(f[g * 4 + 3] * inv);
    *(ushort4*)&dst[g * 4] = o;
  }
}

// ---------- K8: out = ctx @ WKVT[b]^T + bo  (m97-style 128x128, BK=32) ----------
__global__ __launch_bounds__(256, 4) void out_gemm(
    const U16* __restrict__ Ahi, const U16* __restrict__ WKVT,
    const float* __restrict__ bias, float* __restrict__ C) {
  __shared__ __align__(16) U16 Us[2 * 128 * 32];
  const int tid = threadIdx.x, w = tid >> 6, lane = tid & 63;
  const int quad = lane >> 4, l16 = lane & 15;
  const int rowA0 = blockIdx.y * 128, colB0 = blockIdx.x * 128;
  const int wm = w & 1, wn = w >> 1;
  const int K = 768;
  const U16* Bb = WKVT + (size_t)(blockIdx.y >> 6) * 589824;
  f32x4 acc[4][4] = {};
  const U16* srcs[4];
  unsigned ldsoff[4];
#pragma unroll
  for (int t = 0; t < 4; ++t) {
    int c = w * 4 + t, cc = c & 7, buf = c >> 3;
    const U16* base = buf ? Bb : Ahi;
    int r0 = buf ? colB0 : rowA0;
    srcs[t] = base + (size_t)(r0 + cc * 16 + (lane >> 2)) * K + (lane & 3) * 8;
    ldsoff[t] = c * 512;
  }
  for (int k0 = 0; k0 < K; k0 += 32) {
#pragma unroll
    for (int t = 0; t < 4; ++t) gl2lds16(srcs[t] + k0, &Us[ldsoff[t]]);
    __syncthreads();
    bf16x8 ah[4];
#pragma unroll
    for (int i = 0; i < 4; ++i)
      ah[i] = *(const bf16x8*)&Us[(wm * 64 + i * 16 + l16) * 32 + quad * 8];
#pragma unroll
    for (int j = 0; j < 4; ++j) {
      bf16x8 bh = *(const bf16x8*)&Us[4096 + (wn * 64 + j * 16 + l16) * 32 + quad * 8];
#pragma unroll
      for (int i = 0; i < 4; ++i)
        acc[i][j] = __builtin_amdgcn_mfma_f32_16x16x32_bf16(ah[i], bh, acc[i][j], 0, 0, 0);
    }
    __syncthreads();
  }
#pragma unroll
  for (int i = 0; i < 4; ++i) {
    int row = rowA0 + wm * 64 + i * 16 + quad * 4;
#pragma unroll
    for (int j = 0; j < 4; ++j) {
      int col = colB0 + wn * 64 + j * 16 + l16;
      float bvv = bias[col];
#pragma unroll
      for (int r = 0; r < 4; ++r)
        C[(size_t)(row + r) * H_ + col] = acc[i][j][r] + bvv;
    }
  }
}

extern "C" void kernel_launch(void* const* d_in, const int* in_sizes, int n_in,
                              void* d_out, int out_size, void* d_ws, size_t ws_size,
                              hipStream_t stream) {
  const float* hs = (const float*)d_in[0];
  const float* Wq = (const float*)d_in[1];
  const float* bq = (const float*)d_in[2];
  const float* Wk = (const float*)d_in[3];
  const float* bk = (const float*)d_in[4];
  const float* Wv = (const float*)d_in[5];
  const float* bv = (const float*)d_in[6];
  const float* Wo = (const float*)d_in[7];
  const float* bo = (const float*)d_in[8];
  const float* P  = (const float*)d_in[9];
  float* out = (float*)d_out;

  char* ws = (char*)d_ws;
  size_t off = 0;
  auto alloc = [&](size_t bytes) -> void* {
    void* p = ws + off;
    off = (off + bytes + 255) & ~(size_t)255;
    return p;
  };
  U16*   hs_hi = (U16*)alloc(50331648);     // [32768,768] bf16 (reused as ctx)
  float* WqpF  = (float*)alloc(2359296);
  float* WkpF  = (float*)alloc(2359296);
  float* bqpF  = (float*)alloc(3072);
  float* bkpF  = (float*)alloc(3072);
  U16*   WcatH = (U16*)alloc(3538944);      // [2304,768] bf16
  U16*   WoTH  = (U16*)alloc(1179648);      // [768,768] bf16 (Wo^T)
  float* biasC = (float*)alloc(9216);
  U16*   qp    = (U16*)alloc(50331648);     // [48,8192,64] bf16 row-major
  U16*   kpT   = (U16*)alloc(50331648);     // [48,64,8192] bf16 transposed
  U16*   vT    = (U16*)alloc(50331648);     // [48,64,8192] bf16 transposed
  float* kvM   = (float*)alloc(786432);     // [48,64,64] fp32 (m-major)
  float* ksumF = (float*)alloc(12288);      // [48,64] fp32 (contiguous after kvM)
  U16*   WKVT  = (U16*)alloc(4718592);      // [4][768][768] bf16
  U16*   ctx   = hs_hi;                     // hs dead after QKV GEMM: reuse

  zero_f32<<<dim3(780), dim3(256), 0, stream>>>(kvM, 199680);  // kvM + ksumF
  cvt_f32_bf16<<<dim3(24576), dim3(256), 0, stream>>>(hs, hs_hi, 6291456);
  fold_proj<<<dim3(192, 12, 2), dim3(256), 0, stream>>>(Wq, bq, Wk, bk, P, WqpF, bqpF, WkpF, bkpF);
  build_cat_t<<<dim3(12, 12, 4), dim3(256), 0, stream>>>(WqpF, WkpF, Wv, Wo, WcatH, WoTH);
  build_bias<<<dim3(9), dim3(256), 0, stream>>>(bqpF, bkpF, bv, biasC);
  gemm_qkv<<<dim3(512), dim3(256), 0, stream>>>(hs_hi, WcatH, biasC, qp, kpT, vT, ksumF);
  kv_accum_mfma<<<dim3(16, 48), dim3(256), 0, stream>>>(kpT, vT, kvM);
  wkv_build<<<dim3(6, 48), dim3(256), 0, stream>>>(kvM, WoTH, WKVT);
  qpn_scale<<<dim3(128, 48), dim3(256), 0, stream>>>(qp, ksumF, ctx);
  out_gemm<<<dim3(6, 256), dim3(256), 0, stream>>>(ctx, WKVT, bo, out);
}

// Round 5
// 518.615 us; speedup vs baseline: 1.0588x; 1.0588x over previous
//
#include <hip/hip_runtime.h>
#include <hip/hip_bf16.h>

// Performer-style linear attention: B=4, S=8192, H=768, NH=12, HD=64, M=64.
// Round 9: tail consolidation on the WKV factorization.
//   out[s,c] = sum_{h,m} (qp[b,h,s,m]/(n+eps)) * WKV[b,h,m,c] + bo,
//   WKV[b,h,m,c] = sum_d kv[b,h,m,d] * Wo[h*64+d, c].
// Changes vs r8: qpn_scale is IN-PLACE on qp (coalesced, no ctx buffer);
// out_gemm is a clone of gemm_qkv's proven persistent K-loop (BK=64 = one
// head per K-step, counted vmcnt(8), swizzled LDS, setprio, 3-tile sweep).
// Pipeline:
//   K0 zero kvM[48][64][64] + ksumF[48][64]
//   K1 cvt hs -> bf16
//   K2 fold P into Wq/Wk (Wqp = Wq * blockdiag(P)) [fp32]
//   K3 build B^T concat weights [Wqp|Wkp|Wv] + WoT as bf16 (tile transpose), bias
//   K4 gemm_qkv (persistent 128x128) -> qp, kpT, vT, ksumF
//   K5 kv_accum_mfma -> kvM[bh][m][d] fp32
//   K6 wkv_build: WKVT[b][c][h*64+m] = sum_d WoT[c][h*64+d]*kv[m][d]
//   K7 qpn_scale: n = qp . ksum; qp <- qp/(n+eps)  (in place)
//   K8 out_gemm: out = qpn @ WKVT[b]^T + bo  (persistent 128x128, BK=64)

#define S_    8192
#define H_    768
#define NH_   12
#define EPS_  1e-6f

typedef unsigned short U16;
typedef short bf16x8 __attribute__((ext_vector_type(8)));
typedef float f32x4  __attribute__((ext_vector_type(4)));

__device__ __forceinline__ U16 f2b(float x) {            // fp32 -> bf16 RNE
  unsigned u = __float_as_uint(x);
  return (U16)((u + 0x7fffu + ((u >> 16) & 1u)) >> 16);
}
__device__ __forceinline__ float b2f(U16 h) {
  return __uint_as_float(((unsigned)h) << 16);
}
__device__ __forceinline__ void gl2lds16(const void* g, void* l) {
  __builtin_amdgcn_global_load_lds(
      (const __attribute__((address_space(1))) void*)g,
      (__attribute__((address_space(3))) void*)l, 16, 0, 0);
}

// ---------- K0: zero scratch ----------
__global__ void zero_f32(float* __restrict__ p, int n) {
  int i = blockIdx.x * 256 + threadIdx.x;
  if (i < n) p[i] = 0.f;
}

// ---------- K1: fp32 -> bf16 ----------
__global__ void cvt_f32_bf16(const float* __restrict__ src, U16* __restrict__ hi, int n4) {
  int i = blockIdx.x * 256 + threadIdx.x;
  if (i >= n4) return;
  float4 x = ((const float4*)src)[i];
  ushort4 h;
  h.x = f2b(x.x); h.y = f2b(x.y); h.z = f2b(x.z); h.w = f2b(x.w);
  ((ushort4*)hi)[i] = h;
}

// ---------- K2: fold P into Wq / Wk (and biases) ----------
__global__ void fold_proj(const float* __restrict__ Wq, const float* __restrict__ bq,
                          const float* __restrict__ Wk, const float* __restrict__ bk,
                          const float* __restrict__ P,
                          float* __restrict__ Wqp, float* __restrict__ bqp,
                          float* __restrict__ Wkp, float* __restrict__ bkp) {
  __shared__ float Pl[64 * 64];
  __shared__ float WL[4 * 64];
  int h = blockIdx.y, kc = blockIdx.x, tid = threadIdx.x;
  const float* W  = blockIdx.z ? Wk : Wq;
  const float* bb = blockIdx.z ? bk : bq;
  float* Wout = blockIdx.z ? Wkp : Wqp;
  float* bout = blockIdx.z ? bkp : bqp;
  const float4* P4 = (const float4*)(P + (size_t)h * 4096);
#pragma unroll
  for (int i = 0; i < 4; ++i) ((float4*)Pl)[tid + i * 256] = P4[tid + i * 256];
  WL[tid] = W[(size_t)(kc * 4 + (tid >> 6)) * H_ + h * 64 + (tid & 63)];
  __syncthreads();
  int kl = tid >> 6, m = tid & 63;
  float acc = 0.f;
#pragma unroll
  for (int d = 0; d < 64; ++d) acc += WL[kl * 64 + d] * Pl[d * 64 + m];
  Wout[(size_t)(kc * 4 + kl) * H_ + h * 64 + m] = acc;
  if (kc == 0 && tid < 64) {
    float a2 = 0.f;
    for (int d = 0; d < 64; ++d) a2 += bb[h * 64 + d] * Pl[d * 64 + tid];
    bout[h * 64 + tid] = a2;
  }
}

// ---------- K3: coalesced tile-transpose build of bf16 weights ----------
__global__ void build_cat_t(const float* __restrict__ Wqp, const float* __restrict__ Wkp,
                            const float* __restrict__ Wv,  const float* __restrict__ Wo,
                            U16* __restrict__ WcatH, U16* __restrict__ WoTH) {
  __shared__ float T[64][68];
  const int kb = blockIdx.x, rb = blockIdx.y, mat = blockIdx.z;
  const int tid = threadIdx.x;
  const float* W = mat == 0 ? Wqp : (mat == 1 ? Wkp : (mat == 2 ? Wv : Wo));
#pragma unroll
  for (int p = 0; p < 4; ++p) {
    int idx = tid + p * 256;                 // 1024 float4s
    int rr = idx >> 4, c4 = (idx & 15) * 4;
    float4 v = *(const float4*)&W[(size_t)(kb * 64 + rr) * H_ + rb * 64 + c4];
    T[rr][c4] = v.x; T[rr][c4 + 1] = v.y; T[rr][c4 + 2] = v.z; T[rr][c4 + 3] = v.w;
  }
  __syncthreads();
  U16* dst = mat == 3 ? WoTH : WcatH;
  const int rbase = (mat == 3 ? 0 : mat * 768) + rb * 64;
#pragma unroll
  for (int p = 0; p < 4; ++p) {
    int idx = tid + p * 256;                 // 4096 ushort4s
    int r2 = idx >> 4, c2 = (idx & 15) * 4;
    ushort4 o;
    o.x = f2b(T[c2 + 0][r2]); o.y = f2b(T[c2 + 1][r2]);
    o.z = f2b(T[c2 + 2][r2]); o.w = f2b(T[c2 + 3][r2]);
    *(ushort4*)&dst[(size_t)(rbase + r2) * H_ + kb * 64 + c2] = o;
  }
}

__global__ void build_bias(const float* __restrict__ bqp, const float* __restrict__ bkp,
                           const float* __restrict__ bv, float* __restrict__ biasC) {
  int i = blockIdx.x * 256 + threadIdx.x;
  if (i >= 2304) return;
  biasC[i] = i < 768 ? bqp[i] : (i < 1536 ? bkp[i - 768] : bv[i - 1536]);
}

// ---------- K4: persistent 128x128 bf16 GEMM + fused maxexp epilogue ----------
__global__ __launch_bounds__(256, 2) void gemm_qkv(
    const U16* __restrict__ Ahi, const U16* __restrict__ Bhi,
    const float* __restrict__ bias,
    U16* __restrict__ qp, U16* __restrict__ kpT, U16* __restrict__ vT,
    float* __restrict__ ksumF) {
  __shared__ __align__(16) U16 Us[32768];            // [buf][A/B][128][64] bf16
  const int tid = threadIdx.x, w = tid >> 6, lane = tid & 63;
  const int quad = lane >> 4, l16 = lane & 15;
  const int b = blockIdx.x;                          // 512 persistent blocks
  const int mt = b & 255, nt0 = b >> 8;
  const int rowA0 = mt * 128;
  const int wm = w & 1, wn = w >> 1;
  const U16* srcA[4];
  int rowBl[4];
  unsigned ldsc[4];
  const int kch = ((lane & 7) ^ (lane >> 3)) * 8;    // pre-swizzled src chunk
#pragma unroll
  for (int t = 0; t < 4; ++t) {
    int c = w * 4 + t;
    int row = c * 8 + (lane >> 3);
    srcA[t] = Ahi + (size_t)(rowA0 + row) * H_ + kch;
    rowBl[t] = row;
    ldsc[t] = (unsigned)c * 512;
  }
  auto stage = [&](int jn, int tn, int bi) {
    const int colB = (nt0 + 2 * jn) * 128;
    unsigned ub = (unsigned)bi * 16384u;
#pragma unroll
    for (int t = 0; t < 4; ++t) {
      gl2lds16(srcA[t] + tn * 64, &Us[ub + ldsc[t]]);
      gl2lds16(Bhi + (size_t)(colB + rowBl[t]) * H_ + tn * 64 + kch,
               &Us[ub + 8192u + ldsc[t]]);
    }
  };

  stage(0, 0, 0);
  for (int jj = 0; jj < 9; ++jj) {
    const int colB0 = (nt0 + 2 * jj) * 128;
    f32x4 acc[4][4] = {};
    for (int t = 0; t < 12; ++t) {
      const bool more = !(jj == 8 && t == 11);
      if (more) {
        if (t < 11) stage(jj, t + 1, (t + 1) & 1);
        else        stage(jj + 1, 0, 0);
        asm volatile("s_waitcnt vmcnt(8)" ::: "memory");
      } else {
        asm volatile("s_waitcnt vmcnt(0)" ::: "memory");
      }
      __builtin_amdgcn_sched_barrier(0);
      __builtin_amdgcn_s_barrier();
      __builtin_amdgcn_sched_barrier(0);
      const unsigned ab = (unsigned)(t & 1) * 16384u;
      bf16x8 ah[4][2], bh[4][2];
#pragma unroll
      for (int i = 0; i < 4; ++i)
#pragma unroll
        for (int ks = 0; ks < 2; ++ks)
          ah[i][ks] = *(const bf16x8*)&Us[ab +
              (unsigned)((wm * 64 + i * 16 + l16) * 64 +
                         (((ks * 4 + quad) ^ (l16 & 7)) * 8))];
#pragma unroll
      for (int j = 0; j < 4; ++j)
#pragma unroll
        for (int ks = 0; ks < 2; ++ks)
          bh[j][ks] = *(const bf16x8*)&Us[ab + 8192u +
              (unsigned)((wn * 64 + j * 16 + l16) * 64 +
                         (((ks * 4 + quad) ^ (l16 & 7)) * 8))];
      asm volatile("s_waitcnt lgkmcnt(0)" ::: "memory");
      __builtin_amdgcn_sched_barrier(0);
      __builtin_amdgcn_s_setprio(1);
#pragma unroll
      for (int ks = 0; ks < 2; ++ks)
#pragma unroll
        for (int j = 0; j < 4; ++j)
#pragma unroll
          for (int i = 0; i < 4; ++i)
            acc[i][j] = __builtin_amdgcn_mfma_f32_16x16x32_bf16(
                ah[i][ks], bh[j][ks], acc[i][j], 0, 0, 0);
      __builtin_amdgcn_s_setprio(0);
      __builtin_amdgcn_sched_barrier(0);
      __builtin_amdgcn_s_barrier();
      __builtin_amdgcn_sched_barrier(0);
    }
    // ---- epilogue for this tile (no LDS use; overlaps next stage)
    const int col64 = colB0 + wn * 64;
    float bj[4];
#pragma unroll
    for (int j = 0; j < 4; ++j) bj[j] = bias[col64 + j * 16 + l16];
    if (col64 < 768) {                            // q logits -> row-major qp
      const int h = col64 >> 6;
#pragma unroll
      for (int i = 0; i < 4; ++i) {
#pragma unroll
        for (int r = 0; r < 4; ++r) {
          int row = rowA0 + wm * 64 + i * 16 + quad * 4 + r;
          float v0 = acc[i][0][r] + bj[0], v1 = acc[i][1][r] + bj[1];
          float v2 = acc[i][2][r] + bj[2], v3 = acc[i][3][r] + bj[3];
          float mx = fmaxf(fmaxf(v0, v1), fmaxf(v2, v3));
          mx = fmaxf(mx, __shfl_xor(mx, 1));
          mx = fmaxf(mx, __shfl_xor(mx, 2));
          mx = fmaxf(mx, __shfl_xor(mx, 4));
          mx = fmaxf(mx, __shfl_xor(mx, 8));
          int bb = row >> 13, s = row & 8191;
          size_t base = ((size_t)(bb * NH_ + h) * S_ + s) * 64 + l16;
          qp[base +  0] = f2b(__expf(v0 - mx));
          qp[base + 16] = f2b(__expf(v1 - mx));
          qp[base + 32] = f2b(__expf(v2 - mx));
          qp[base + 48] = f2b(__expf(v3 - mx));
        }
      }
    } else {                                      // k (exp) or v -> transposed
      const int isv = col64 >= 1536;
      const int h = (col64 - (isv ? 1536 : 768)) >> 6;
      U16* dstT = isv ? vT : kpT;
      const int bh2 = (rowA0 >> 13) * NH_ + h;
      float pk[4] = {0.f, 0.f, 0.f, 0.f};
#pragma unroll
      for (int i = 0; i < 4; ++i) {
        float er[4][4];                           // [j][r]
#pragma unroll
        for (int r = 0; r < 4; ++r) {
          float v0 = acc[i][0][r] + bj[0], v1 = acc[i][1][r] + bj[1];
          float v2 = acc[i][2][r] + bj[2], v3 = acc[i][3][r] + bj[3];
          if (!isv) {
            float mx = fmaxf(fmaxf(v0, v1), fmaxf(v2, v3));
            mx = fmaxf(mx, __shfl_xor(mx, 1));
            mx = fmaxf(mx, __shfl_xor(mx, 2));
            mx = fmaxf(mx, __shfl_xor(mx, 4));
            mx = fmaxf(mx, __shfl_xor(mx, 8));
            v0 = __expf(v0 - mx); v1 = __expf(v1 - mx);
            v2 = __expf(v2 - mx); v3 = __expf(v3 - mx);
          }
          er[0][r] = v0; er[1][r] = v1; er[2][r] = v2; er[3][r] = v3;
        }
        if (!isv) {
#pragma unroll
          for (int j = 0; j < 4; ++j)
            pk[j] += er[j][0] + er[j][1] + er[j][2] + er[j][3];
        }
        int n = rowA0 + wm * 64 + i * 16 + quad * 4;   // 4-aligned
        int s = n & 8191;
#pragma unroll
        for (int j = 0; j < 4; ++j) {
          ushort4 o;
          o.x = f2b(er[j][0]); o.y = f2b(er[j][1]);
          o.z = f2b(er[j][2]); o.w = f2b(er[j][3]);
          *(ushort4*)&dstT[((size_t)bh2 * 64 + j * 16 + l16) * S_ + s] = o;
        }
      }
      if (!isv) {                                  // ksum partial (64 rows)
#pragma unroll
        for (int j = 0; j < 4; ++j) {
          pk[j] += __shfl_xor(pk[j], 16);
          pk[j] += __shfl_xor(pk[j], 32);
        }
        if (quad == 0) {
#pragma unroll
          for (int j = 0; j < 4; ++j)
            atomicAdd(&ksumF[bh2 * 64 + j * 16 + l16], pk[j]);
        }
      }
    }
  }
}

// ---------- K5: kv summary via MFMA -> kvM[bh][m][d] fp32 ----------
__global__ __launch_bounds__(256, 4) void kv_accum_mfma(
    const U16* __restrict__ kpT, const U16* __restrict__ vT,
    float* __restrict__ kvM) {
  __shared__ __align__(16) U16 Us[2 * 64 * 64];   // [0:4096]=vT tile, [4096:8192]=kpT
  const int tid = threadIdx.x, w = tid >> 6, lane = tid & 63;
  const int quad = lane >> 4, l16 = lane & 15;
  const int bh = blockIdx.y;
  const int n0 = blockIdx.x * 512;
  const U16* srcs[4];
  unsigned ldsoff[4];
#pragma unroll
  for (int t = 0; t < 4; ++t) {
    int c = w * 4 + t, buf = c >> 3;              // 0..15; buf 0 = vT, 1 = kpT
    int r = (c & 7) * 8 + (lane >> 3);
    const U16* base = buf ? kpT : vT;
    srcs[t] = base + ((size_t)bh * 64 + r) * S_ + n0 + (lane & 7) * 8;
    ldsoff[t] = buf * 4096 + (c & 7) * 512;
  }
  f32x4 acc[4] = {};
  for (int nc = 0; nc < 512; nc += 64) {
#pragma unroll
    for (int t = 0; t < 4; ++t) gl2lds16(srcs[t] + nc, &Us[ldsoff[t]]);
    __syncthreads();
#pragma unroll
    for (int k0 = 0; k0 < 64; k0 += 32) {
      bf16x8 av = *(const bf16x8*)&Us[(w * 16 + l16) * 64 + k0 + quad * 8];
#pragma unroll
      for (int j = 0; j < 4; ++j) {
        bf16x8 bk = *(const bf16x8*)&Us[4096 + (j * 16 + l16) * 64 + k0 + quad * 8];
        acc[j] = __builtin_amdgcn_mfma_f32_16x16x32_bf16(av, bk, acc[j], 0, 0, 0);
      }
    }
    __syncthreads();
  }
  // acc[j][r]: d = w*16+quad*4+r, m = j*16+l16 -> kvM[bh][m][d]
#pragma unroll
  for (int j = 0; j < 4; ++j)
#pragma unroll
    for (int r = 0; r < 4; ++r)
      atomicAdd(&kvM[((size_t)bh * 64 + j * 16 + l16) * 64 + w * 16 + quad * 4 + r],
                acc[j][r]);
}

// ---------- K6: WKVT[b][c][h*64+m] = sum_d WoT[c][h*64+d] * kv[m][d] ----------
__global__ __launch_bounds__(256) void wkv_build(
    const float* __restrict__ kvM, const U16* __restrict__ WoTH,
    U16* __restrict__ WKVT) {
  __shared__ float kvL[64][65];
  __shared__ U16  WoL[128][66];
  const int tid = threadIdx.x;
  const int cB = blockIdx.x * 128, bh = blockIdx.y;
  const int b = bh / NH_, h = bh - b * NH_;
#pragma unroll
  for (int p = 0; p < 16; ++p) {
    int idx = tid + p * 256;                   // 4096 floats
    kvL[idx >> 6][idx & 63] = kvM[(size_t)bh * 4096 + idx];
  }
#pragma unroll
  for (int p = 0; p < 32; ++p) {
    int idx = tid + p * 256;                   // 8192 u16
    WoL[idx >> 6][idx & 63] = WoTH[(size_t)(cB + (idx >> 6)) * H_ + h * 64 + (idx & 63)];
  }
  __syncthreads();
  const int c = tid & 127, m0 = (tid >> 7) * 32;
  float acc[32] = {};
  for (int d = 0; d < 64; ++d) {
    float wv = b2f(WoL[c][d]);
#pragma unroll
    for (int mm = 0; mm < 32; ++mm) acc[mm] += wv * kvL[m0 + mm][d];
  }
  U16* dst = WKVT + (size_t)b * 589824 + (size_t)(cB + c) * H_ + h * 64 + m0;
#pragma unroll
  for (int mm = 0; mm < 32; mm += 4) {
    ushort4 o;
    o.x = f2b(acc[mm]); o.y = f2b(acc[mm + 1]);
    o.z = f2b(acc[mm + 2]); o.w = f2b(acc[mm + 3]);
    *(ushort4*)&dst[mm] = o;
  }
}

// ---------- K7: qp <- qp/(n+eps) in place; n = qp . ksum ----------
// grid (128 s-chunks, 48 bh), 256 threads: 64 rows/block, 4 threads/row.
__global__ __launch_bounds__(256) void qpn_scale(
    U16* __restrict__ qp, const float* __restrict__ ksumF) {
  __shared__ float ks[64];
  const int tid = threadIdx.x;
  const int bh = blockIdx.y, s0 = blockIdx.x * 64;
  if (tid < 64) ks[tid] = ksumF[bh * 64 + tid];
  __syncthreads();
  const int row = tid >> 2, q = tid & 3;
  size_t src = ((size_t)bh * S_ + s0 + row) * 64 + q * 16;
  bf16x8 x0 = *(const bf16x8*)&qp[src];
  bf16x8 x1 = *(const bf16x8*)&qp[src + 8];
  float f[16];
  float n = 0.f;
#pragma unroll
  for (int e = 0; e < 8; ++e) {
    f[e] = b2f((U16)x0[e]);     n += f[e] * ks[q * 16 + e];
    f[e + 8] = b2f((U16)x1[e]); n += f[e + 8] * ks[q * 16 + 8 + e];
  }
  n += __shfl_xor(n, 1);
  n += __shfl_xor(n, 2);
  const float inv = 1.f / (n + EPS_);
#pragma unroll
  for (int g = 0; g < 4; ++g) {
    ushort4 o;
    o.x = f2b(f[g * 4 + 0] * inv); o.y = f2b(f[g * 4 + 1] * inv);
    o.z = f2b(f[g * 4 + 2] * inv); o.w = f2b(f[g * 4 + 3] * inv);
    *(ushort4*)&qp[src + g * 4] = o;
  }
}

// ---------- K8: out = qpn @ WKVT[b]^T + bo (persistent 128x128, BK=64) -------
// Clone of gemm_qkv's K-loop. 512 blocks (2/CU), block b: mt = b&255 fixed,
// nt = (b>>8)*3 + jj, jj=0..2. K-step t = head t: A-tile = qpn[bh0+t][s0..][:].
__global__ __launch_bounds__(256, 2) void out_gemm(
    const U16* __restrict__ qpn, const U16* __restrict__ WKVT,
    const float* __restrict__ bo, float* __restrict__ out) {
  __shared__ __align__(16) U16 Us[32768];
  const int tid = threadIdx.x, w = tid >> 6, lane = tid & 63;
  const int quad = lane >> 4, l16 = lane & 15;
  const int b = blockIdx.x;                          // 512 persistent blocks
  const int mt = b & 255, nt0 = b >> 8;
  const int rowA0 = mt * 128;
  const int batch = mt >> 6, s0 = (mt & 63) * 128;
  const int bh0 = batch * NH_;
  const int wm = w & 1, wn = w >> 1;
  const int kch = ((lane & 7) ^ (lane >> 3)) * 8;
  int rowc[4];
  unsigned ldsc[4];
#pragma unroll
  for (int t = 0; t < 4; ++t) {
    rowc[t] = (w * 4 + t) * 8 + (lane >> 3);
    ldsc[t] = (unsigned)(w * 4 + t) * 512;
  }
  const U16* wb = WKVT + (size_t)batch * 589824;
  auto stage = [&](int jn, int tn, int bi) {
    const int colB = (nt0 * 3 + jn) * 128;
    unsigned ub = (unsigned)bi * 16384u;
    const U16* abase = qpn + ((size_t)(bh0 + tn) * S_ + s0) * 64 + kch;
    const U16* bbase = wb + (size_t)colB * H_ + tn * 64 + kch;
#pragma unroll
    for (int t = 0; t < 4; ++t) {
      gl2lds16(abase + rowc[t] * 64, &Us[ub + ldsc[t]]);
      gl2lds16(bbase + (size_t)rowc[t] * H_, &Us[ub + 8192u + ldsc[t]]);
    }
  };

  stage(0, 0, 0);
  for (int jj = 0; jj < 3; ++jj) {
    const int colB0 = (nt0 * 3 + jj) * 128;
    f32x4 acc[4][4] = {};
    for (int t = 0; t < 12; ++t) {
      const bool more = !(jj == 2 && t == 11);
      if (more) {
        if (t < 11) stage(jj, t + 1, (t + 1) & 1);
        else        stage(jj + 1, 0, 0);
        asm volatile("s_waitcnt vmcnt(8)" ::: "memory");
      } else {
        asm volatile("s_waitcnt vmcnt(0)" ::: "memory");
      }
      __builtin_amdgcn_sched_barrier(0);
      __builtin_amdgcn_s_barrier();
      __builtin_amdgcn_sched_barrier(0);
      const unsigned ab = (unsigned)(t & 1) * 16384u;
      bf16x8 ah[4][2], bh[4][2];
#pragma unroll
      for (int i = 0; i < 4; ++i)
#pragma unroll
        for (int ks = 0; ks < 2; ++ks)
          ah[i][ks] = *(const bf16x8*)&Us[ab +
              (unsigned)((wm * 64 + i * 16 + l16) * 64 +
                         (((ks * 4 + quad) ^ (l16 & 7)) * 8))];
#pragma unroll
      for (int j = 0; j < 4; ++j)
#pragma unroll
        for (int ks = 0; ks < 2; ++ks)
          bh[j][ks] = *(const bf16x8*)&Us[ab + 8192u +
              (unsigned)((wn * 64 + j * 16 + l16) * 64 +
                         (((ks * 4 + quad) ^ (l16 & 7)) * 8))];
      asm volatile("s_waitcnt lgkmcnt(0)" ::: "memory");
      __builtin_amdgcn_sched_barrier(0);
      __builtin_amdgcn_s_setprio(1);
#pragma unroll
      for (int ks = 0; ks < 2; ++ks)
#pragma unroll
        for (int j = 0; j < 4; ++j)
#pragma unroll
          for (int i = 0; i < 4; ++i)
            acc[i][j] = __builtin_amdgcn_mfma_f32_16x16x32_bf16(
                ah[i][ks], bh[j][ks], acc[i][j], 0, 0, 0);
      __builtin_amdgcn_s_setprio(0);
      __builtin_amdgcn_sched_barrier(0);
      __builtin_amdgcn_s_barrier();
      __builtin_amdgcn_sched_barrier(0);
    }
    // ---- epilogue (no LDS use; overlaps next stage)
#pragma unroll
    for (int i = 0; i < 4; ++i) {
      int row = rowA0 + wm * 64 + i * 16 + quad * 4;
#pragma unroll
      for (int j = 0; j < 4; ++j) {
        int col = colB0 + wn * 64 + j * 16 + l16;
        float bvv = bo[col];
#pragma unroll
        for (int r = 0; r < 4; ++r)
          out[(size_t)(row + r) * H_ + col] = acc[i][j][r] + bvv;
      }
    }
  }
}

extern "C" void kernel_launch(void* const* d_in, const int* in_sizes, int n_in,
                              void* d_out, int out_size, void* d_ws, size_t ws_size,
                              hipStream_t stream) {
  const float* hs = (const float*)d_in[0];
  const float* Wq = (const float*)d_in[1];
  const float* bq = (const float*)d_in[2];
  const float* Wk = (const float*)d_in[3];
  const float* bk = (const float*)d_in[4];
  const float* Wv = (const float*)d_in[5];
  const float* bv = (const float*)d_in[6];
  const float* Wo = (const float*)d_in[7];
  const float* bo = (const float*)d_in[8];
  const float* P  = (const float*)d_in[9];
  float* out = (float*)d_out;

  char* ws = (char*)d_ws;
  size_t off = 0;
  auto alloc = [&](size_t bytes) -> void* {
    void* p = ws + off;
    off = (off + bytes + 255) & ~(size_t)255;
    return p;
  };
  U16*   hs_hi = (U16*)alloc(50331648);     // [32768,768] bf16
  float* WqpF  = (float*)alloc(2359296);
  float* WkpF  = (float*)alloc(2359296);
  float* bqpF  = (float*)alloc(3072);
  float* bkpF  = (float*)alloc(3072);
  U16*   WcatH = (U16*)alloc(3538944);      // [2304,768] bf16
  U16*   WoTH  = (U16*)alloc(1179648);      // [768,768] bf16 (Wo^T)
  float* biasC = (float*)alloc(9216);
  U16*   qp    = (U16*)alloc(50331648);     // [48,8192,64] bf16 row-major
  U16*   kpT   = (U16*)alloc(50331648);     // [48,64,8192] bf16 transposed
  U16*   vT    = (U16*)alloc(50331648);     // [48,64,8192] bf16 transposed
  float* kvM   = (float*)alloc(786432);     // [48,64,64] fp32 (m-major)
  float* ksumF = (float*)alloc(12288);      // [48,64] fp32 (contiguous after kvM)
  U16*   WKVT  = (U16*)alloc(4718592);      // [4][768][768] bf16

  zero_f32<<<dim3(780), dim3(256), 0, stream>>>(kvM, 199680);  // kvM + ksumF
  cvt_f32_bf16<<<dim3(24576), dim3(256), 0, stream>>>(hs, hs_hi, 6291456);
  fold_proj<<<dim3(192, 12, 2), dim3(256), 0, stream>>>(Wq, bq, Wk, bk, P, WqpF, bqpF, WkpF, bkpF);
  build_cat_t<<<dim3(12, 12, 4), dim3(256), 0, stream>>>(WqpF, WkpF, Wv, Wo, WcatH, WoTH);
  build_bias<<<dim3(9), dim3(256), 0, stream>>>(bqpF, bkpF, bv, biasC);
  gemm_qkv<<<dim3(512), dim3(256), 0, stream>>>(hs_hi, WcatH, biasC, qp, kpT, vT, ksumF);
  kv_accum_mfma<<<dim3(16, 48), dim3(256), 0, stream>>>(kpT, vT, kvM);
  wkv_build<<<dim3(6, 48), dim3(256), 0, stream>>>(kvM, WoTH, WKVT);
  qpn_scale<<<dim3(128, 48), dim3(256), 0, stream>>>(qp, ksumF);
  out_gemm<<<dim3(512), dim3(256), 0, stream>>>(qp, WKVT, bo, out);
}